// Round 1
// baseline (611.325 us; speedup 1.0000x reference)
//
#include <hip/hip_runtime.h>
#include <cstdint>
#include <cstddef>

#define TSEQ 2048
#define DDIM 1024

typedef _Float16 f16;
typedef _Float16 f16x4 __attribute__((ext_vector_type(4)));
typedef _Float16 f16x8 __attribute__((ext_vector_type(8)));
typedef float f32x4 __attribute__((ext_vector_type(4)));

// 16B of zeros for out-of-range (causal pad) staging loads
__device__ __align__(16) static const unsigned char g_zero16[16] = {};

__device__ __forceinline__ void gload_lds16(const void* g, void* l) {
  __builtin_amdgcn_global_load_lds(
      (const __attribute__((address_space(1))) void*)g,
      (__attribute__((address_space(3))) void*)l, 16, 0, 0);
}

// ---------------- fp32 -> fp16 convert (vectorized) ----------------
__global__ void cvt_f32_f16(const float* __restrict__ src, f16* __restrict__ dst, int n4) {
  int i = blockIdx.x * 256 + threadIdx.x;
  if (i >= n4) return;
  float4 v = ((const float4*)src)[i];
  f16x4 h = { (f16)v.x, (f16)v.y, (f16)v.z, (f16)v.w };
  ((f16x4*)dst)[i] = h;
}

// ------- weight convert+transpose: w[o][i][W] -> wh[o][w*D + i] -------
__global__ void cvt_w_transpose(const float* __restrict__ qw, const float* __restrict__ kw,
                                f16* __restrict__ qwh, f16* __restrict__ kwh) {
  __shared__ float tile[64 * 17];
  int o = blockIdx.x;
  const float* src;
  f16* dst;
  if (o < 1024) { src = qw + (size_t)o * 16384; dst = qwh + (size_t)o * 16384; }
  else          { src = kw + (size_t)(o - 1024) * 16384; dst = kwh + (size_t)(o - 1024) * 16384; }
  for (int i0 = 0; i0 < 1024; i0 += 64) {
    __syncthreads();
    #pragma unroll
    for (int p = 0; p < 4; p++) {
      int idx = p * 256 + threadIdx.x;           // flat = ii*16 + w
      float v = src[i0 * 16 + idx];
      tile[(idx >> 4) * 17 + (idx & 15)] = v;    // [ii][w] padded
    }
    __syncthreads();
    #pragma unroll
    for (int p = 0; p < 4; p++) {
      int idx = p * 256 + threadIdx.x;           // w = idx/64, ii = idx%64
      int w = idx >> 6, ii = idx & 63;
      dst[w * 1024 + i0 + ii] = (f16)tile[ii * 17 + w];
    }
  }
}

// ---------------- MFMA GEMM: conv-as-GEMM / plain GEMM ----------------
// MODE 0: A=xh, blockIdx.y selects q (KW=16) / k (KW=16) / v (KW=1), fp16 out
// MODE 1: A=outh, p-projection, fp32 out to d_out
template<int MODE>
__global__ __launch_bounds__(256, 2) void gemm_k(
    const f16* __restrict__ Abase,
    const f16* __restrict__ Bq, const f16* __restrict__ Bk, const f16* __restrict__ Bv,
    const float* __restrict__ bq, const float* __restrict__ bk, const float* __restrict__ bv,
    f16* __restrict__ oq, f16* __restrict__ okk, f16* __restrict__ ov,
    float* __restrict__ of)
{
  __shared__ f16 As[128 * 32];
  __shared__ f16 Bs[128 * 32];
  const int tid = threadIdx.x;
  const int lane = tid & 63;
  const int wid = tid >> 6;
  const int mtile = blockIdx.x;
  const int yt = blockIdx.y;

  const f16* Bp; const float* bias; f16* oh = nullptr; float* ofp = nullptr;
  int K, KW, n0;
  if (MODE == 0) {
    if (yt < 8)       { Bp = Bq; bias = bq; oh = oq;  K = 16384; KW = 16; n0 = yt * 128; }
    else if (yt < 16) { Bp = Bk; bias = bk; oh = okk; K = 16384; KW = 16; n0 = (yt - 8) * 128; }
    else              { Bp = Bv; bias = bv; oh = ov;  K = 1024;  KW = 1;  n0 = (yt - 16) * 128; }
  } else {
    Bp = Bq; bias = bq; ofp = of; K = 1024; KW = 1; n0 = yt * 128;
  }

  const int m0 = mtile * 128;
  const int bT = m0 & ~(TSEQ - 1);     // batch base row
  const int t0 = m0 & (TSEQ - 1);      // within-batch t

  const int srow = lane >> 2;          // staging row within 16-row chunk
  const int scol = (lane & 3) * 8;     // staging col (halves)
  const int wm = wid & 1;
  const int wn = wid >> 1;

  f32x4 acc[4][4] = {};

  for (int kk = 0; kk < K; kk += 32) {
    __syncthreads();
    if (wid < 2) {
      const int w = kk >> 10;                    // conv tap (0 for K=1024)
      const int i0k = (kk & (DDIM - 1)) + scol;  // channel offset
      #pragma unroll
      for (int c = 0; c < 4; c++) {
        const int r = wid * 64 + c * 16 + srow;
        const int srcT = t0 + r + w - (KW - 1);
        const void* g = (srcT >= 0)
            ? (const void*)(Abase + (((size_t)(bT + srcT)) << 10) + i0k)
            : (const void*)g_zero16;
        gload_lds16(g, (void*)&As[(wid * 64 + c * 16) * 32]);
      }
    } else {
      #pragma unroll
      for (int c = 0; c < 4; c++) {
        const int r = (wid - 2) * 64 + c * 16 + srow;
        const void* g = (const void*)(Bp + (size_t)(n0 + r) * K + kk + scol);
        gload_lds16(g, (void*)&Bs[((wid - 2) * 64 + c * 16) * 32]);
      }
    }
    __syncthreads();
    f16x8 af[4], bf[4];
    #pragma unroll
    for (int i = 0; i < 4; i++) {
      af[i] = *(const f16x8*)&As[(wm * 64 + i * 16 + (lane & 15)) * 32 + (lane >> 4) * 8];
      bf[i] = *(const f16x8*)&Bs[(wn * 64 + i * 16 + (lane & 15)) * 32 + (lane >> 4) * 8];
    }
    #pragma unroll
    for (int i = 0; i < 4; i++)
      #pragma unroll
      for (int j = 0; j < 4; j++)
        acc[i][j] = __builtin_amdgcn_mfma_f32_16x16x32_f16(af[i], bf[j], acc[i][j], 0, 0, 0);
  }

  // epilogue: C/D layout col=lane&15, row=(lane>>4)*4+reg
  const int crow = (lane >> 4) * 4;
  const int ccol = lane & 15;
  #pragma unroll
  for (int j = 0; j < 4; j++) {
    const int col = n0 + wn * 64 + j * 16 + ccol;
    const float bvl = bias[col];
    #pragma unroll
    for (int i = 0; i < 4; i++) {
      #pragma unroll
      for (int r = 0; r < 4; r++) {
        const int row = m0 + wm * 64 + i * 16 + crow + r;
        const float val = acc[i][j][r] + bvl;
        if (MODE == 1) ofp[(size_t)row * DDIM + col] = val;
        else           oh[(size_t)row * DDIM + col] = (f16)val;
      }
    }
  }
}

// ------- log-sparse scores: s[bh,e,t] = q[t]·k[(t+2^e)%T] * scale -------
__global__ void score_k(const f16* __restrict__ qh, const f16* __restrict__ kh,
                        float* __restrict__ scores) {
  int bid = blockIdx.x;            // 256 blocks
  int bh = bid >> 3, tc = bid & 7;
  int b = bh >> 4, h = bh & 15;
  int t = tc * 256 + threadIdx.x;
  const f16* qrow = qh + (((size_t)(b * TSEQ + t)) << 10) + h * 64;
  float qv[64];
  #pragma unroll
  for (int c = 0; c < 8; c++) {
    f16x8 v = *(const f16x8*)(qrow + c * 8);
    #pragma unroll
    for (int j = 0; j < 8; j++) qv[c * 8 + j] = (float)v[j];
  }
  #pragma unroll
  for (int e = 0; e < 8; e++) {
    int ts = t + (1 << e);
    if (ts >= TSEQ) ts -= TSEQ;      // jnp.roll wraps
    const f16* krow = kh + (((size_t)(b * TSEQ + ts)) << 10) + h * 64;
    float s = 0.f;
    #pragma unroll
    for (int c = 0; c < 8; c++) {
      f16x8 v = *(const f16x8*)(krow + c * 8);
      #pragma unroll
      for (int j = 0; j < 8; j++) s += qv[c * 8 + j] * (float)v[j];
    }
    scores[((size_t)(bh * 8 + e) << 11) + t] = s * 0.125f;
  }
}

// ---- in-place softmax over T per (b,h,e) row: 256 rows of 2048 ----
__global__ void softmax_k(float* __restrict__ scores) {
  __shared__ float red[4];
  int row = blockIdx.x;
  float* p = scores + ((size_t)row << 11);
  int tid = threadIdx.x;
  float v[8];
  float4 a = ((const float4*)p)[tid * 2];
  float4 b = ((const float4*)p)[tid * 2 + 1];
  v[0] = a.x; v[1] = a.y; v[2] = a.z; v[3] = a.w;
  v[4] = b.x; v[5] = b.y; v[6] = b.z; v[7] = b.w;
  float m = v[0];
  #pragma unroll
  for (int j = 1; j < 8; j++) m = fmaxf(m, v[j]);
  for (int o = 32; o > 0; o >>= 1) m = fmaxf(m, __shfl_xor(m, o, 64));
  if ((tid & 63) == 0) red[tid >> 6] = m;
  __syncthreads();
  m = fmaxf(fmaxf(red[0], red[1]), fmaxf(red[2], red[3]));
  __syncthreads();
  float s = 0.f;
  #pragma unroll
  for (int j = 0; j < 8; j++) { v[j] = __expf(v[j] - m); s += v[j]; }
  for (int o = 32; o > 0; o >>= 1) s += __shfl_xor(s, o, 64);
  if ((tid & 63) == 0) red[tid >> 6] = s;
  __syncthreads();
  s = (red[0] + red[1]) + (red[2] + red[3]);
  float inv = 1.0f / s;
  float4 o1 = make_float4(v[0] * inv, v[1] * inv, v[2] * inv, v[3] * inv);
  float4 o2 = make_float4(v[4] * inv, v[5] * inv, v[6] * inv, v[7] * inv);
  ((float4*)p)[tid * 2] = o1;
  ((float4*)p)[tid * 2 + 1] = o2;
}

// ------- local windowed attention + log-sparse combine -> outh -------
__global__ __launch_bounds__(256) void attn_out_k(
    const f16* __restrict__ qh, const f16* __restrict__ kh, const f16* __restrict__ vh,
    const float* __restrict__ alpha, f16* __restrict__ outh)
{
  __shared__ f16 qL[128 * 64];     // 16 KB
  __shared__ f16 vL[271 * 64];     // 33.9 KB: rows t0-15 .. t0+255 (wrap)
  __shared__ float scL[128 * 16];  // 8 KB
  __shared__ float aL[8 * 128];    // 4 KB
  const int bh = blockIdx.x, tc = blockIdx.y;
  const int b = bh >> 4, h = bh & 15;
  const int t0 = tc * 128;
  const int tid = threadIdx.x;
  const size_t base = (((size_t)(b * TSEQ)) << 10) + h * 64;

  // phase 1: cooperative loads
  for (int idx = tid; idx < 128 * 8; idx += 256) {
    int r = idx >> 3, c = idx & 7;
    *(uint4*)&qL[r * 64 + c * 8] = *(const uint4*)(qh + base + (((size_t)(t0 + r)) << 10) + c * 8);
  }
  for (int idx = tid; idx < 271 * 8; idx += 256) {
    int j = idx >> 3, c = idx & 7;
    int r = t0 - 15 + j;
    uint4 val;
    if (r < 0) val = make_uint4(0, 0, 0, 0);
    else {
      int rr = (r >= TSEQ) ? r - TSEQ : r;     // wrap for log-sparse rows
      val = *(const uint4*)(vh + base + (((size_t)rr) << 10) + c * 8);
    }
    *(uint4*)&vL[j * 64 + c * 8] = val;
  }
  {
    int e = tid >> 5, t4 = (tid & 31) * 4;
    *(float4*)&aL[e * 128 + t4] =
        *(const float4*)(alpha + ((size_t)(bh * 8 + e) << 11) + t0 + t4);
  }
  __syncthreads();

  // phase 2: local scores (zero-pad rows give score exactly 0, kept in softmax)
  {
    const int tl = tid & 127;
    const int wg = tid >> 7;
    float qv[64];
    #pragma unroll
    for (int c = 0; c < 8; c++) {
      f16x8 v = *(const f16x8*)&qL[tl * 64 + c * 8];
      #pragma unroll
      for (int j = 0; j < 8; j++) qv[c * 8 + j] = (float)v[j];
    }
    #pragma unroll
    for (int wi = 0; wi < 8; wi++) {
      const int w = wg * 8 + wi;
      const int r = t0 + tl - 15 + w;
      float s = 0.f;
      if (r >= 0) {
        const f16* kr = kh + base + (((size_t)r) << 10);
        #pragma unroll
        for (int c = 0; c < 8; c++) {
          f16x8 v = *(const f16x8*)(kr + c * 8);
          #pragma unroll
          for (int j = 0; j < 8; j++) s += qv[c * 8 + j] * (float)v[j];
        }
      }
      scL[tl * 16 + w] = s * 0.125f;
    }
  }
  __syncthreads();

  // phase 3: 16-wide softmax per t
  if (tid < 128) {
    float sc[16];
    float m = -1e30f;
    #pragma unroll
    for (int w = 0; w < 16; w++) { sc[w] = scL[tid * 16 + w]; m = fmaxf(m, sc[w]); }
    float sum = 0.f;
    #pragma unroll
    for (int w = 0; w < 16; w++) { sc[w] = __expf(sc[w] - m); sum += sc[w]; }
    float inv = 1.0f / sum;
    #pragma unroll
    for (int w = 0; w < 16; w++) scL[tid * 16 + w] = sc[w] * inv;
  }
  __syncthreads();

  // phase 4: out = local + log-sparse
  {
    const int tl = tid >> 1;
    const int d0 = (tid & 1) * 32;
    float accv[32] = {};
    #pragma unroll
    for (int w = 0; w < 16; w++) {
      const float pw_ = scL[tl * 16 + w];
      const f16* vr = &vL[(tl + w) * 64 + d0];
      #pragma unroll
      for (int c = 0; c < 4; c++) {
        f16x8 v = *(const f16x8*)(vr + c * 8);
        #pragma unroll
        for (int j = 0; j < 8; j++) accv[c * 8 + j] += pw_ * (float)v[j];
      }
    }
    #pragma unroll
    for (int e = 0; e < 8; e++) {
      const float a = aL[e * 128 + tl];
      const f16* vr = &vL[(tl + 15 + (1 << e)) * 64 + d0];
      #pragma unroll
      for (int c = 0; c < 4; c++) {
        f16x8 v = *(const f16x8*)(vr + c * 8);
        #pragma unroll
        for (int j = 0; j < 8; j++) accv[c * 8 + j] += a * (float)v[j];
      }
    }
    f16* orow = outh + base + (((size_t)(t0 + tl)) << 10) + d0;
    #pragma unroll
    for (int c = 0; c < 4; c++) {
      f16x8 v;
      #pragma unroll
      for (int j = 0; j < 8; j++) v[j] = (f16)accv[c * 8 + j];
      *(f16x8*)(orow + c * 8) = v;
    }
  }
}

extern "C" void kernel_launch(void* const* d_in, const int* in_sizes, int n_in,
                              void* d_out, int out_size, void* d_ws, size_t ws_size,
                              hipStream_t stream) {
  (void)in_sizes; (void)n_in; (void)out_size; (void)ws_size;
  const float* x   = (const float*)d_in[0];
  const float* q_w = (const float*)d_in[1];
  const float* q_b = (const float*)d_in[2];
  const float* k_w = (const float*)d_in[3];
  const float* k_b = (const float*)d_in[4];
  const float* v_w = (const float*)d_in[5];
  const float* v_b = (const float*)d_in[6];
  const float* p_w = (const float*)d_in[7];
  const float* p_b = (const float*)d_in[8];
  float* out = (float*)d_out;

  char* ws = (char*)d_ws;
  f16* xh      = (f16*)(ws);                 //  8.4 MB
  f16* qwh     = (f16*)(ws + 8388608);       // 33.6 MB  [o][w*D+i]
  f16* kwh     = (f16*)(ws + 41943040);      // 33.6 MB
  f16* vwh     = (f16*)(ws + 75497472);      //  2.1 MB
  f16* pwh     = (f16*)(ws + 77594624);      //  2.1 MB
  f16* qh      = (f16*)(ws + 79691776);      //  8.4 MB  (B,T,D)
  f16* kh      = (f16*)(ws + 88080384);      //  8.4 MB
  f16* vh      = (f16*)(ws + 96468992);      //  8.4 MB
  f16* outh    = (f16*)(ws + 104857600);     //  8.4 MB
  float* alpha = (float*)(ws + 113246208);   //  2.1 MB  (B*H*E, T) scores->alpha
  // total 115.4 MB

  cvt_f32_f16<<<4096, 256, 0, stream>>>(x, xh, 1048576);
  cvt_f32_f16<<<1024, 256, 0, stream>>>(v_w, vwh, 262144);
  cvt_f32_f16<<<1024, 256, 0, stream>>>(p_w, pwh, 262144);
  cvt_w_transpose<<<2048, 256, 0, stream>>>(q_w, k_w, qwh, kwh);

  // fused q/k/v GEMM: yt 0-7 q (K=16384), 8-15 k, 16-23 v (K=1024)
  gemm_k<0><<<dim3(32, 24), 256, 0, stream>>>(xh, qwh, kwh, vwh, q_b, k_b, v_b,
                                              qh, kh, vh, nullptr);

  score_k<<<256, 256, 0, stream>>>(qh, kh, alpha);
  softmax_k<<<256, 256, 0, stream>>>(alpha);
  attn_out_k<<<dim3(32, 16), 256, 0, stream>>>(qh, kh, vh, alpha, outh);

  // final projection -> fp32 d_out
  gemm_k<1><<<dim3(32, 8), 256, 0, stream>>>(outh, pwh, nullptr, nullptr, p_b,
                                             nullptr, nullptr, nullptr, nullptr,
                                             nullptr, out);
}